// Round 1
// baseline (245.962 us; speedup 1.0000x reference)
//
#include <hip/hip_runtime.h>

#define FEAT 128
#define HID  128
#define XS_S 132  // 128 nodes + 4 pad; multiple of 4 keeps b128 alignment

// ---------------------------------------------------------------------------
// Kernel 1: [A|B] = X @ [W1[:128] | W1[128:]]  (N x 256 concat, fp32)
// One block = 128 nodes x 128 concat-cols (g=0 -> A-half, g=1 -> B-half).
// Micro-tile 4 nodes x 16 cols per thread (64 acc VGPRs). K chunked by 32:
// xs = X^T chunk (32k x 128n, 16.9 KB), ws = W chunk (32k x 128c, 16 KB)
// -> 33.3 KB LDS, ~4 blocks/CU. Grid = 2*ceil(N/128) = 782 linear blocks with
// a bijective XCD-chunked swizzle so both column-halves of one X-tile run
// back-to-back on the SAME XCD -> X fetched ~once into each L2 (was 4x).
// b1 is folded into the A-half epilogue so edge_z doesn't need it.
// ---------------------------------------------------------------------------
__global__ __launch_bounds__(256) void gemm_ab(
    const float* __restrict__ X, const float* __restrict__ W1,
    const float* __restrict__ b1, float* __restrict__ A,
    float* __restrict__ B, int N) {
  __shared__ float xs[32 * XS_S];
  __shared__ float ws[32 * 128];
  const int t = threadIdx.x;

  // bijective chunked XCD swizzle (nb need not be %8==0)
  const int nb = gridDim.x;
  const int q = nb >> 3, r = nb & 7;
  const int xcd = blockIdx.x & 7, bidx = blockIdx.x >> 3;
  const int nw = (xcd < r ? xcd * (q + 1) : r * (q + 1) + (xcd - r) * q) + bidx;
  const int n0 = (nw >> 1) * 128;
  const int g = nw & 1;  // 0 -> A (W1 rows 0..127), 1 -> B (W1 rows 128..255)
  const float* Wbase = W1 + (size_t)g * 128 * HID;
  float* Obase = g ? B : A;

  const int tn = t & 31;  // node group: nodes tn*4 .. tn*4+3
  const int tc = t >> 5;  // col group:  cols  tc*16 .. tc*16+15

  float acc[4][16];
#pragma unroll
  for (int rr = 0; rr < 4; ++rr)
#pragma unroll
    for (int c = 0; c < 16; ++c) acc[rr][c] = 0.f;

  const int ln = t >> 3;       // staging node 0..31 (+rep*32)
  const int lf = (t & 7) * 4;  // staging k-local float4 base

  for (int kc = 0; kc < 4; ++kc) {
    __syncthreads();
    // stage X chunk transposed: xs[k_local][node]
#pragma unroll
    for (int rep = 0; rep < 4; ++rep) {
      const int nl = ln + rep * 32;
      const int n = n0 + nl;
      float4 v = make_float4(0.f, 0.f, 0.f, 0.f);
      if (n < N) v = *(const float4*)(X + (size_t)n * FEAT + kc * 32 + lf);
      xs[(lf + 0) * XS_S + nl] = v.x;
      xs[(lf + 1) * XS_S + nl] = v.y;
      xs[(lf + 2) * XS_S + nl] = v.z;
      xs[(lf + 3) * XS_S + nl] = v.w;
    }
    // stage W chunk: ws[k_local][col]  (32 x 128 floats = 1024 float4s)
#pragma unroll
    for (int rep = 0; rep < 4; ++rep) {
      const int idx = rep * 256 + t;   // 0..1023 float4s
      const int wr = idx >> 5;         // 0..31 (k_local)
      const int c4 = (idx & 31) * 4;   // 0..124
      *(float4*)&ws[wr * 128 + c4] =
          *(const float4*)(Wbase + (size_t)(kc * 32 + wr) * HID + c4);
    }
    __syncthreads();

#pragma unroll 8
    for (int k = 0; k < 32; ++k) {
      const float4 xv = *(const float4*)&xs[k * XS_S + tn * 4];
      const float4 w0 = *(const float4*)&ws[k * 128 + tc * 16 + 0];
      const float4 w1 = *(const float4*)&ws[k * 128 + tc * 16 + 4];
      const float4 w2 = *(const float4*)&ws[k * 128 + tc * 16 + 8];
      const float4 w3 = *(const float4*)&ws[k * 128 + tc * 16 + 12];
      const float xr[4] = {xv.x, xv.y, xv.z, xv.w};
#pragma unroll
      for (int rr = 0; rr < 4; ++rr) {
        acc[rr][0]  = fmaf(xr[rr], w0.x, acc[rr][0]);
        acc[rr][1]  = fmaf(xr[rr], w0.y, acc[rr][1]);
        acc[rr][2]  = fmaf(xr[rr], w0.z, acc[rr][2]);
        acc[rr][3]  = fmaf(xr[rr], w0.w, acc[rr][3]);
        acc[rr][4]  = fmaf(xr[rr], w1.x, acc[rr][4]);
        acc[rr][5]  = fmaf(xr[rr], w1.y, acc[rr][5]);
        acc[rr][6]  = fmaf(xr[rr], w1.z, acc[rr][6]);
        acc[rr][7]  = fmaf(xr[rr], w1.w, acc[rr][7]);
        acc[rr][8]  = fmaf(xr[rr], w2.x, acc[rr][8]);
        acc[rr][9]  = fmaf(xr[rr], w2.y, acc[rr][9]);
        acc[rr][10] = fmaf(xr[rr], w2.z, acc[rr][10]);
        acc[rr][11] = fmaf(xr[rr], w2.w, acc[rr][11]);
        acc[rr][12] = fmaf(xr[rr], w3.x, acc[rr][12]);
        acc[rr][13] = fmaf(xr[rr], w3.y, acc[rr][13]);
        acc[rr][14] = fmaf(xr[rr], w3.z, acc[rr][14]);
        acc[rr][15] = fmaf(xr[rr], w3.w, acc[rr][15]);
      }
    }
  }

  // epilogue: fold b1 into the A-half so edge_z needn't read it
  float4 bb[4];
#pragma unroll
  for (int c = 0; c < 4; ++c) bb[c] = make_float4(0.f, 0.f, 0.f, 0.f);
  if (g == 0) {
#pragma unroll
    for (int c = 0; c < 4; ++c) bb[c] = *(const float4*)(b1 + tc * 16 + c * 4);
  }
#pragma unroll
  for (int rr = 0; rr < 4; ++rr) {
    const int n = n0 + tn * 4 + rr;
    if (n < N) {
      float* o = Obase + (size_t)n * HID + tc * 16;
#pragma unroll
      for (int c = 0; c < 4; ++c) {
        *(float4*)(o + c * 4) = make_float4(
            acc[rr][c * 4 + 0] + bb[c].x, acc[rr][c * 4 + 1] + bb[c].y,
            acc[rr][c * 4 + 2] + bb[c].z, acc[rr][c * 4 + 3] + bb[c].w);
      }
    }
  }
}

// ---------------------------------------------------------------------------
// Kernel 2: CSR row offsets from sorted src via binary search. rs has N+1 ents.
// ---------------------------------------------------------------------------
__global__ __launch_bounds__(256) void row_offsets(
    const int* __restrict__ src, int* __restrict__ rs, int N, int E) {
  const int n = blockIdx.x * 256 + threadIdx.x;
  if (n > N) return;
  int lo = 0, hi = E;
  while (lo < hi) {
    const int mid = (lo + hi) >> 1;
    if (src[mid] < n) lo = mid + 1; else hi = mid;
  }
  rs[n] = lo;
}

// ---------------------------------------------------------------------------
// Kernel 3: z[e] = W2 . relu(A[src[e]] + B[dst[e]]) + b2   (b1 pre-folded in A)
// 16 lanes per edge (8 floats/lane), 2 edges per 16-lane group, all 8 row
// loads issued before any reduce. 4-step shfl_xor reduce.
// ---------------------------------------------------------------------------
__global__ __launch_bounds__(256) void edge_z(
    const float* __restrict__ A, const float* __restrict__ B,
    const float* __restrict__ W2, const float* __restrict__ b2,
    const int* __restrict__ src, const int* __restrict__ dst,
    float* __restrict__ z, int E) {
  const int g = threadIdx.x >> 4;
  const int l = threadIdx.x & 15;
  const int e0 = blockIdx.x * 32 + g * 2;
  if (e0 >= E) return;
  const int e1 = e0 + 1;
  const bool has1 = e1 < E;

  const int u0 = src[e0], v0 = dst[e0];
  const int u1 = has1 ? src[e1] : u0;
  const int v1 = has1 ? dst[e1] : v0;

  const float4* Au0 = (const float4*)(A + (size_t)u0 * HID) + l * 2;
  const float4* Bv0 = (const float4*)(B + (size_t)v0 * HID) + l * 2;
  const float4* Au1 = (const float4*)(A + (size_t)u1 * HID) + l * 2;
  const float4* Bv1 = (const float4*)(B + (size_t)v1 * HID) + l * 2;

  const float4 a00 = Au0[0], a01 = Au0[1];
  const float4 b00 = Bv0[0], b01 = Bv0[1];
  const float4 a10 = Au1[0], a11 = Au1[1];
  const float4 b10 = Bv1[0], b11 = Bv1[1];

  const float4 w0 = *(const float4*)(W2 + l * 8);
  const float4 w1 = *(const float4*)(W2 + l * 8 + 4);
  const float bias2 = b2[0];

  float p0 = fmaxf(a00.x + b00.x, 0.f) * w0.x
           + fmaxf(a00.y + b00.y, 0.f) * w0.y
           + fmaxf(a00.z + b00.z, 0.f) * w0.z
           + fmaxf(a00.w + b00.w, 0.f) * w0.w
           + fmaxf(a01.x + b01.x, 0.f) * w1.x
           + fmaxf(a01.y + b01.y, 0.f) * w1.y
           + fmaxf(a01.z + b01.z, 0.f) * w1.z
           + fmaxf(a01.w + b01.w, 0.f) * w1.w;
  float p1 = fmaxf(a10.x + b10.x, 0.f) * w0.x
           + fmaxf(a10.y + b10.y, 0.f) * w0.y
           + fmaxf(a10.z + b10.z, 0.f) * w0.z
           + fmaxf(a10.w + b10.w, 0.f) * w0.w
           + fmaxf(a11.x + b11.x, 0.f) * w1.x
           + fmaxf(a11.y + b11.y, 0.f) * w1.y
           + fmaxf(a11.z + b11.z, 0.f) * w1.z
           + fmaxf(a11.w + b11.w, 0.f) * w1.w;

#pragma unroll
  for (int m = 8; m >= 1; m >>= 1) {
    p0 += __shfl_xor(p0, m);
    p1 += __shfl_xor(p1, m);
  }
  if (l == 0) {
    z[e0] = p0 + bias2;
    if (has1) z[e1] = p1 + bias2;
  }
}

// ---------------------------------------------------------------------------
// Kernel 4: per-node log-softmax + K Gumbel rounds. FOUR nodes per wave:
// 16 lanes per node, 2 edges per lane (covers deg<=32; avg deg 16). 4-step
// shfl_xor reduces serve 4 nodes per DS instruction (was: 5-step over 32
// lanes serving 2 nodes) -> ~2.5x less DS-pipe work per node, half the waves.
// Works in ex = exp(s) space: argmax(ex) == argmax(s); fast __logf/__expf.
// ---------------------------------------------------------------------------
__global__ __launch_bounds__(256) void seg_sample(
    const float* __restrict__ z, const float* __restrict__ U,
    const int* __restrict__ dst, const int* __restrict__ rs,
    float* __restrict__ out_sel, float* __restrict__ out_soft,
    int N, int E, int K) {
  const int t = threadIdx.x;
  const int lane = t & 63;
  const int qtr = lane >> 4;   // quarter 0..3: one node each
  const int ql = lane & 15;    // lane within node: edges 2*ql, 2*ql+1
  const int n = blockIdx.x * 16 + (t >> 6) * 4 + qtr;
  const float INVTAU = 1.0f / 0.9991f;

  int start = 0, deg = 0;
  if (n < N) { start = rs[n]; deg = rs[n + 1] - start; }

  if (__all(deg <= 32)) {
    // ---- fast path: 16-lane quarter per node, 2 edges/lane ----
    if (n >= N) return;
    if (deg == 0) {
      if (ql == 0)
        for (int k = 0; k < K; ++k) out_sel[(size_t)k * N + n] = -2147483648.0f;
      return;
    }
    const bool a0 = 2 * ql < deg;
    const bool a1 = 2 * ql + 1 < deg;
    const int e0 = start + 2 * ql;
    const int e1 = e0 + 1;
    const float z0 = a0 ? z[e0] : -INFINITY;
    const float z1 = a1 ? z[e1] : -INFINITY;
    const int d0 = a0 ? dst[e0] : -1;
    const int d1 = a1 ? dst[e1] : -1;

    float zmax = fmaxf(z0, z1);
#pragma unroll
    for (int m = 8; m >= 1; m >>= 1) zmax = fmaxf(zmax, __shfl_xor(zmax, m));
    float den = (a0 ? __expf(z0 - zmax) : 0.f) + (a1 ? __expf(z1 - zmax) : 0.f);
#pragma unroll
    for (int m = 8; m >= 1; m >>= 1) den += __shfl_xor(den, m);
    const float logd = __logf(den);
    const float lp0 = (z0 - zmax) - logd;  // per-edge log-prob
    const float lp1 = (z1 - zmax) - logd;

    for (int k = 0; k < K; ++k) {
      float ex0 = 0.f, ex1 = 0.f;
      if (a0) {
        const float uu = U[(size_t)k * E + e0];
        const float gum = -__logf(-__logf(uu));
        ex0 = __expf((lp0 + gum) * INVTAU);  // exp(s); s in [-19,15] -> safe
      }
      if (a1) {
        const float uu = U[(size_t)k * E + e1];
        const float gum = -__logf(-__logf(uu));
        ex1 = __expf((lp1 + gum) * INVTAU);
      }
      // lane-local pair combine (tie -> larger dst, matching reference)
      float d2 = ex0 + ex1;
      float mx;
      int md;
      if (ex1 > ex0)      { mx = ex1; md = d1; }
      else if (ex1 < ex0) { mx = ex0; md = d0; }
      else                { mx = ex0; md = max(d0, d1); }
#pragma unroll
      for (int m = 8; m >= 1; m >>= 1) {
        d2 += __shfl_xor(d2, m);
        const float ox = __shfl_xor(mx, m);
        const int od = __shfl_xor(md, m);
        if (ox > mx) { mx = ox; md = od; }
        else if (ox == mx) md = max(md, od);
      }
      if (ql == 0) out_sel[(size_t)k * N + n] = (float)md;
      const float inv = __builtin_amdgcn_rcpf(d2);
      if (a0) out_soft[(size_t)k * E + e0] = ex0 * inv;
      if (a1) out_soft[(size_t)k * E + e1] = ex1 * inv;
    }
    return;
  }

  // ---- general path (some deg > 32, ~5 nodes): full wave per node, x4 ----
  const int wbase = blockIdx.x * 16 + (t >> 6) * 4;
  for (int j = 0; j < 4; ++j) {
    const int nn = wbase + j;
    if (nn >= N) continue;
    const int st = rs[nn];
    const int dg = rs[nn + 1] - st;
    if (dg == 0) {
      if (lane == 0)
        for (int k = 0; k < K; ++k) out_sel[(size_t)k * N + nn] = -2147483648.0f;
      continue;
    }
    float zmax = -INFINITY;
    for (int c = lane; c < dg; c += 64) zmax = fmaxf(zmax, z[st + c]);
#pragma unroll
    for (int m = 32; m >= 1; m >>= 1) zmax = fmaxf(zmax, __shfl_xor(zmax, m));
    float den = 0.f;
    for (int c = lane; c < dg; c += 64) den += expf(z[st + c] - zmax);
#pragma unroll
    for (int m = 32; m >= 1; m >>= 1) den += __shfl_xor(den, m);
    const float logd = logf(den);

    for (int k = 0; k < K; ++k) {
      float m2 = -INFINITY;
      for (int c = lane; c < dg; c += 64) {
        const int e = st + c;
        const float gum = -logf(-logf(U[(size_t)k * E + e]));
        const float s = ((z[e] - zmax) - logd + gum) * INVTAU;
        m2 = fmaxf(m2, s);
      }
#pragma unroll
      for (int m = 32; m >= 1; m >>= 1) m2 = fmaxf(m2, __shfl_xor(m2, m));
      float d2 = 0.f;
      int cand = -1;
      for (int c = lane; c < dg; c += 64) {
        const int e = st + c;
        const float gum = -logf(-logf(U[(size_t)k * E + e]));
        const float s = ((z[e] - zmax) - logd + gum) * INVTAU;
        d2 += expf(s - m2);
        if (s >= m2) cand = max(cand, dst[e]);
      }
#pragma unroll
      for (int m = 32; m >= 1; m >>= 1) d2 += __shfl_xor(d2, m);
#pragma unroll
      for (int m = 32; m >= 1; m >>= 1) cand = max(cand, __shfl_xor(cand, m));
      if (lane == 0) out_sel[(size_t)k * N + nn] = (float)cand;
      for (int c = lane; c < dg; c += 64) {
        const int e = st + c;
        const float gum = -logf(-logf(U[(size_t)k * E + e]));
        const float s = ((z[e] - zmax) - logd + gum) * INVTAU;
        out_soft[(size_t)k * E + e] = expf(s - m2) / d2;
      }
    }
  }
}

// ---------------------------------------------------------------------------
extern "C" void kernel_launch(void* const* d_in, const int* in_sizes, int n_in,
                              void* d_out, int out_size, void* d_ws, size_t ws_size,
                              hipStream_t stream) {
  const float* X  = (const float*)d_in[0];  // (N, 128)
  const float* W1 = (const float*)d_in[1];  // (256, 128)
  const float* b1 = (const float*)d_in[2];  // (128,)
  const float* W2 = (const float*)d_in[3];  // (128,)
  const float* b2 = (const float*)d_in[4];  // (1,)
  const float* U  = (const float*)d_in[5];  // (K, E)
  const int* src  = (const int*)d_in[6];    // (E,) sorted
  const int* dst  = (const int*)d_in[7];    // (E,)
  const int E = in_sizes[6];
  const int K = in_sizes[5] / E;
  const int N = in_sizes[0] / FEAT;

  // workspace: A (N*128 f32) | B (N*128 f32) | z (E f32) | rs (N+1 i32)
  float* A = (float*)d_ws;
  float* B = A + (size_t)N * HID;
  float* z = B + (size_t)N * HID;
  int* rs  = (int*)(z + E);

  float* out_sel  = (float*)d_out;                  // (K, N) as f32
  float* out_soft = (float*)d_out + (size_t)K * N;  // (K, E)

  hipLaunchKernelGGL(gemm_ab, dim3(2 * ((N + 127) / 128)), dim3(256), 0, stream,
                     X, W1, b1, A, B, N);
  hipLaunchKernelGGL(row_offsets, dim3((N + 256) / 256), dim3(256), 0, stream,
                     src, rs, N, E);
  hipLaunchKernelGGL(edge_z, dim3((E + 31) / 32), dim3(256), 0, stream,
                     A, B, W2, b2, src, dst, z, E);
  hipLaunchKernelGGL(seg_sample, dim3((N + 15) / 16), dim3(256), 0, stream,
                     z, U, dst, rs, out_sel, out_soft, N, E, K);
}